// Round 4
// baseline (3271.894 us; speedup 1.0000x reference)
//
#include <hip/hip_runtime.h>
#include <math.h>

#define W_WIN 5
#define NSUB 2
#define MAX_SEG 64
#define MAX_T 256
#define NWGB 8          // workgroups per batch (ODE)

__device__ __forceinline__ float softplusf(float v) {
    // jax.nn.softplus == logaddexp(v, 0) == max(v,0) + log1p(exp(-|v|))
    return fmaxf(v, 0.0f) + log1pf(expf(-fabsf(v)));
}

// ---------------- wave-level numpy-faithful reductions (plan kernel) ----------------
// lane l holds e0 = a[l], e1 = a[l+64]. numpy pairwise sum for n=128:
// r_k = serial fold a[k]+a[k+8]+...+a[k+120]; then ((r0+r1)+(r2+r3))+((r4+r5)+(r6+r7)).
__device__ __forceinline__ float npsum128(float e0, float e1) {
    int lane = threadIdx.x & 63;
    int k = lane & 7;
    float r = __shfl(e0, k, 64);
    #pragma unroll
    for (int m = 1; m < 8; ++m) r += __shfl(e0, k + 8 * m, 64);
    #pragma unroll
    for (int m = 0; m < 8; ++m) r += __shfl(e1, k + 8 * m, 64);
    float r0 = __shfl(r, 0, 64), r1 = __shfl(r, 1, 64), r2 = __shfl(r, 2, 64), r3 = __shfl(r, 3, 64);
    float r4 = __shfl(r, 4, 64), r5 = __shfl(r, 5, 64), r6 = __shfl(r, 6, 64), r7 = __shfl(r, 7, 64);
    return ((r0 + r1) + (r2 + r3)) + ((r4 + r5) + (r6 + r7));
}

__device__ __forceinline__ float wmax128(float e0, float e1) {
    float m = fmaxf(e0, e1);        // max is exact regardless of order
    #pragma unroll
    for (int s = 1; s < 64; s <<= 1) m = fmaxf(m, __shfl_xor(m, s, 64));
    return m;
}

// ---------------- kernel 1: encoder (also writes traj_t output block) ----------------
__global__ void encode_kernel(const float* __restrict__ emb, const int* __restrict__ hi,
                              const float* __restrict__ w1, const float* __restrict__ b1,
                              const float* __restrict__ w2, const float* __restrict__ b2,
                              float* __restrict__ enc, float* __restrict__ out,
                              int B, int L, int D) {
    __shared__ float x[128];
    __shared__ float h[128];
    int row = blockIdx.x;           // 0 .. B*L-1
    int j = threadIdx.x;            // 0 .. D-1
    int idx = hi[row];
    x[j] = emb[(size_t)idx * D + j];
    __syncthreads();
    float s = b1[j];
    #pragma unroll 8
    for (int i = 0; i < 128; ++i) s += x[i] * w1[i * 128 + j];
    h[j] = fmaxf(s, 0.0f);
    __syncthreads();
    float o = b2[j];
    #pragma unroll 8
    for (int i = 0; i < 128; ++i) o += h[i] * w2[i * 128 + j];
    enc[(size_t)row * D + j] = o;
    int b = row / L, l = row % L;
    size_t OS = 2 + 2 * (size_t)L * D;
    out[(size_t)b * OS + 2 + (size_t)L * D + (size_t)l * D + j] = o;
}

// ---------------- kernel 2: APT partition + plan building (1 wave / batch) ----------------
__global__ __launch_bounds__(64) void plan_kernel(
        const float* __restrict__ enc_all, const float* __restrict__ ht,
        const int* __restrict__ hl, const float* __restrict__ pt,
        float* __restrict__ envs, float* __restrict__ dt_sched,
        int* __restrict__ envid, int* __restrict__ stateidx,
        int* __restrict__ Tcnt, int B, int L, int D) {
    const int b = blockIdx.x;
    const int lane = threadIdx.x;   // 0..63
    const float* encg = enc_all + (size_t)b * L * D;
    const float* times = ht + (size_t)b * L;

    __shared__ float encs[128 * 128];
    __shared__ double cand[160];
    __shared__ double bounds[40];
    __shared__ int starts[40];
    __shared__ int seg_s[40], seg_e[40];
    __shared__ int m_sh;

    // stage enc[b] into LDS (64 KB)
    for (int v = lane; v < 128 * 128 / 4; v += 64)
        ((float4*)encs)[v] = ((const float4*)encg)[v];
    int n = hl[b];
    __syncthreads();

    int nb = 1, ns = 1;             // uniform across the wave
    if (lane == 0) { bounds[0] = (double)times[0]; starts[0] = 0; }
    __syncthreads();

    if (n >= 2 * W_WIN) {
        int j = 0;
        while (j <= n - 2 * W_WIN) {
            const float* r = encs + j * 128;
            float ml0 = (((( r[lane]        + r[128 + lane]) + r[256 + lane]) + r[384 + lane]) + r[512 + lane]) / 5.0f;
            float ml1 = (((( r[64 + lane]   + r[192 + lane]) + r[320 + lane]) + r[448 + lane]) + r[576 + lane]) / 5.0f;
            float mr0 = (((( r[640 + lane]  + r[768 + lane]) + r[896 + lane]) + r[1024 + lane]) + r[1152 + lane]) / 5.0f;
            float mr1 = (((( r[704 + lane]  + r[832 + lane]) + r[960 + lane]) + r[1088 + lane]) + r[1216 + lane]) / 5.0f;
            float mxl = wmax128(ml0, ml1), mxr = wmax128(mr0, mr1);
            float a0 = expf(ml0 - mxl), a1 = expf(ml1 - mxl);
            float c0 = expf(mr0 - mxr), c1 = expf(mr1 - mxr);
            float sl = npsum128(a0, a1), sr = npsum128(c0, c1);
            float p0 = a0 / sl + 1e-8f, p1 = a1 / sl + 1e-8f;
            float q0 = c0 / sr + 1e-8f, q1 = c1 / sr + 1e-8f;
            float sp = npsum128(p0, p1), sq = npsum128(q0, q1);
            p0 /= sp; p1 /= sp; q0 /= sq; q1 /= sq;
            float mv0 = 0.5f * (p0 + q0), mv1 = 0.5f * (p1 + q1);
            float t10 = p0 * logf(p0 / mv0), t11 = p1 * logf(p1 / mv1);
            float t20 = q0 * logf(q0 / mv0), t21 = q1 * logf(q1 / mv1);
            float s1 = npsum128(t10, t11), s2 = npsum128(t20, t21);
            float jsd = 0.5f * s1 + 0.5f * s2;
            if (jsd > 0.5f) {
                if (nb < 39 && ns < 39) {
                    if (lane == 0) {
                        bounds[nb] = ((double)times[j + W_WIN - 1] + (double)times[j + W_WIN]) * 0.5;
                        starts[ns] = j + W_WIN;
                    }
                    nb++; ns++;
                }
                j += W_WIN;
            } else {
                j += 1;
            }
        }
    }
    __syncthreads();

    {
        double lastb = bounds[nb - 1];
        if ((double)times[n - 1] > lastb) {
            if (lane == 0) bounds[nb] = (double)times[n - 1];
            nb++;
        }
    }
    if (lane == 0) {
        for (int si = 0; si < ns; ++si) {
            seg_s[si] = starts[si];
            seg_e[si] = (si + 1 < ns) ? (starts[si + 1] - 1) : (n - 1);
        }
    }
    __syncthreads();

    int C = 0;
    for (int si = 0; si < ns; ++si) {
        int s = seg_s[si], e = seg_e[si];
        if (lane == 0) {
            double t0 = bounds[si];
            double t1 = (si + 1 < nb) ? bounds[si + 1] : bounds[nb - 1];
            // linear merge of sorted(set([t0,t1] + in-range times)); times sorted
            int m = 0;
            cand[m++] = t0;
            for (int l = s; l <= e; ++l) {
                double tv = (double)times[l];
                if (tv < t0 || tv > t1) continue;
                if (tv != cand[m - 1]) cand[m++] = tv;
            }
            if (t1 > cand[m - 1]) cand[m++] = t1;
            // _make_increasing (float64, gap 1e-6)
            for (int k = 1; k < m; ++k)
                if (cand[k] - cand[k - 1] < 1e-6) cand[k] = cand[k - 1] + 1e-6;
            m_sh = m;
        }
        __syncthreads();
        int m = m_sh;
        int K = m - 1;
        if (C + K > MAX_T) K = MAX_T - C;
        for (int k = lane; k < K; k += 64) {
            dt_sched[b * MAX_T + C + k] = (float)(cand[k + 1] - cand[k]);
            envid[b * MAX_T + C + k] = si;
        }
        for (int l = s + lane; l <= e; l += 64) {
            double tv = (double)times[l];
            int best = 0;
            double bd = fabs(cand[0] - tv);
            for (int k = 1; k < m; ++k) {
                double dk = fabs(cand[k] - tv);
                if (dk < bd) { bd = dk; best = k; }
            }
            stateidx[b * L + l] = C + best;
        }
        __syncthreads();
        C += K;
    }

    if (lane == 0) {
        double ptv = (double)pt[b];
        if (ptv > bounds[nb - 1] + 1e-6 && C < MAX_T) {
            double a0d = bounds[nb - 1], a1d = ptv;
            if (a1d - a0d < 1e-6) a1d = a0d + 1e-6;
            dt_sched[b * MAX_T + C] = (float)(a1d - a0d);
            envid[b * MAX_T + C] = ns - 1;
            C++;
        }
        Tcnt[b] = C;
    }
    // per-segment env means (2 dims per lane)
    for (int si = 0; si < ns; ++si) {
        int s = seg_s[si], e = seg_e[si];
        float s0 = 0.0f, s1 = 0.0f;
        for (int l = s; l <= e; ++l) {
            s0 += encs[l * 128 + lane];
            s1 += encs[l * 128 + lane + 64];
        }
        float inv = 1.0f / (float)(e - s + 1);
        envs[((size_t)b * MAX_SEG + si) * 128 + lane] = s0 * inv;
        envs[((size_t)b * MAX_SEG + si) * 128 + lane + 64] = s1 * inv;
    }
}

// ---------------- per-batch slot barrier across NWGB workgroups ----------------
// No RMW: WG g release-publishes its phase into slots[g]; pollers wait until
// min(slots[0..7]) >= phase. Slots are monotone -> no reset/wrap hazard.
// __syncthreads() on entry implies each wave drained its own vmcnt (publish
// stores complete) before tid0 signals -- same protocol rounds 2-3 validated.
__device__ __forceinline__ void bbar(int* slots, int g, int phase) {
    __syncthreads();
    if (threadIdx.x == 0) {
        __threadfence();    // release
        __hip_atomic_store(&slots[g], phase, __ATOMIC_RELAXED, __HIP_MEMORY_SCOPE_AGENT);
        for (;;) {
            int mn = phase;
            #pragma unroll
            for (int j = 0; j < NWGB; ++j) {
                int v = __hip_atomic_load(&slots[j], __ATOMIC_RELAXED, __HIP_MEMORY_SCOPE_AGENT);
                mn = min(mn, v);
            }
            if (mn >= phase) break;
        }
        __threadfence();    // acquire
    }
    __syncthreads();
}

// ---------------- kernel 3: per-batch cooperative ODE, weights in VGPRs ----------------
// grid = 8*NWGB blocks x 512 thr. batch = blockIdx%8 (exit if >= B), g = blockIdx/8.
// WG g owns h1/h2 cols [g*64,g*64+64) and z cols [g*16,g*16+16).
__global__ __launch_bounds__(512, 1) void ode_coop(
    const float* __restrict__ usert, const int* __restrict__ u,
    const float* __restrict__ vw1, const float* __restrict__ vb1,
    const float* __restrict__ vw2, const float* __restrict__ vb2,
    const float* __restrict__ vw3, const float* __restrict__ vb3,
    const float* __restrict__ emb, const int* __restrict__ pos, const int* __restrict__ neg,
    const float* __restrict__ envs, const float* __restrict__ dtsch,
    const int* __restrict__ envid, const int* __restrict__ stidx,
    const int* __restrict__ Tc,
    float* zg, float* h1g, float* h2g, int* barws,
    float* out, int B)
{
    const int batch = blockIdx.x & 7;
    if (batch >= B) return;
    const int g = blockIdx.x >> 3;      // 0..7
    const int tid = threadIdx.x;        // 0..511

    // L1/L2 mapping: cl = col-in-slice (0..63), q = input-quarter (0..7)
    const int cl = tid >> 3, q = tid & 7;
    const int c12 = g * 64 + cl;
    // L3 mapping: c3l = col-in-slice (0..15), r3 = input-range (0..31)
    const int c3l = tid >> 5, r3 = tid & 31;
    const int c3 = g * 16 + c3l;

    __shared__ float xs[256];
    __shared__ float h1s[512];
    __shared__ float h2s[512];
    __shared__ int sidx_sh[128];
    __shared__ float dts_sh[MAX_T];
    __shared__ int sid_sh[MAX_T];

    // ---- preload weight slices into registers, skewed order (static indices!) ----
    float w1r[32], w2r[64], w3r[16];
    #pragma unroll
    for (int k4 = 0; k4 < 8; ++k4) {
        int jj = ((k4 + q) & 7) * 4;
        #pragma unroll
        for (int m = 0; m < 4; ++m)
            w1r[k4 * 4 + m] = vw1[(size_t)(q * 32 + jj + m) * 512 + c12];
    }
    #pragma unroll
    for (int k4 = 0; k4 < 16; ++k4) {
        int jj = ((k4 + 2 * q) & 15) * 4;
        #pragma unroll
        for (int m = 0; m < 4; ++m)
            w2r[k4 * 4 + m] = vw2[(size_t)(q * 64 + jj + m) * 512 + c12];
    }
    #pragma unroll
    for (int k4 = 0; k4 < 4; ++k4) {
        int jj = ((k4 + r3) & 3) * 4;
        #pragma unroll
        for (int m = 0; m < 4; ++m)
            w3r[k4 * 4 + m] = vw3[(size_t)(r3 * 16 + jj + m) * 128 + c3];
    }
    const float bias1 = vb1[c12];
    const float bias2 = vb2[c12];
    const float bias3 = vb3[c3];

    if (tid < 128) sidx_sh[tid] = stidx[batch * 128 + tid];
    // schedule cache: dt + env id per interval (values beyond T never read)
    if (tid < MAX_T) {
        dts_sh[tid] = dtsch[batch * MAX_T + tid];
        sid_sh[tid] = envid[batch * MAX_T + tid];
    }
    __syncthreads();

    const int T = Tc[batch];
    float* zgb  = zg  + batch * 128;
    float* h1gb = h1g + batch * 512;
    float* h2gb = h2g + batch * 512;
    int* slots = barws + batch * 32;    // 8 ints used, 128-B stride per batch
    const size_t OS = 2 + 2 * (size_t)128 * 128;
    float* outb = out + (size_t)batch * OS;

    // init z + m=0 records (g==0 writes; others just advance lp)
    int lp = 0;
    if (g == 0 && tid < 128) {
        float z0 = usert[(size_t)u[batch] * 128 + tid];
        zgb[tid] = z0;
        int l = 0;
        while (l < 128 && sidx_sh[l] == 0) { outb[2 + (size_t)l * 128 + tid] = z0; ++l; }
    }
    while (lp < 128 && sidx_sh[lp] == 0) ++lp;
    int phase = 0;
    bbar(slots, g, ++phase);        // publish z0

    for (int t = 0; t < T; ++t) {
        const int si = sid_sh[t];
        const float hdt = dts_sh[t] * 0.5f;                     // dt / NSUB
        const float* envp = envs + ((size_t)batch * MAX_SEG + si) * 128;
        float zn = 0.0f;
        #pragma unroll
        for (int sub = 0; sub < NSUB; ++sub) {
            // stage x = [z | env]
            if (tid < 128) xs[tid] = zgb[tid];
            else if (tid < 256) xs[tid] = envp[tid - 128];
            __syncthreads();
            // ---- layer 1: 256 -> 512, partials over q, reduce 8 lanes ----
            float acc = 0.0f;
            #pragma unroll
            for (int k4 = 0; k4 < 8; ++k4) {
                int off = q * 32 + ((k4 + q) & 7) * 4;
                float4 xv = *(const float4*)(xs + off);
                acc += w1r[k4 * 4 + 0] * xv.x + w1r[k4 * 4 + 1] * xv.y
                     + w1r[k4 * 4 + 2] * xv.z + w1r[k4 * 4 + 3] * xv.w;
            }
            #pragma unroll
            for (int s = 1; s < 8; s <<= 1) acc += __shfl_xor(acc, s, 64);
            if (q == 0) h1gb[c12] = softplusf(acc + bias1);
            bbar(slots, g, ++phase);        // h1 complete
            h1s[tid] = h1gb[tid];
            __syncthreads();
            // ---- layer 2: 512 -> 512 ----
            acc = 0.0f;
            #pragma unroll
            for (int k4 = 0; k4 < 16; ++k4) {
                int off = q * 64 + ((k4 + 2 * q) & 15) * 4;
                float4 xv = *(const float4*)(h1s + off);
                acc += w2r[k4 * 4 + 0] * xv.x + w2r[k4 * 4 + 1] * xv.y
                     + w2r[k4 * 4 + 2] * xv.z + w2r[k4 * 4 + 3] * xv.w;
            }
            #pragma unroll
            for (int s = 1; s < 8; s <<= 1) acc += __shfl_xor(acc, s, 64);
            if (q == 0) h2gb[c12] = softplusf(acc + bias2);
            bbar(slots, g, ++phase);        // h2 complete
            h2s[tid] = h2gb[tid];
            __syncthreads();
            // ---- layer 3: 512 -> 128 + Euler update ----
            acc = 0.0f;
            #pragma unroll
            for (int k4 = 0; k4 < 4; ++k4) {
                int off = r3 * 16 + ((k4 + r3) & 3) * 4;
                float4 xv = *(const float4*)(h2s + off);
                acc += w3r[k4 * 4 + 0] * xv.x + w3r[k4 * 4 + 1] * xv.y
                     + w3r[k4 * 4 + 2] * xv.z + w3r[k4 * 4 + 3] * xv.w;
            }
            #pragma unroll
            for (int s = 1; s < 32; s <<= 1) acc += __shfl_xor(acc, s, 64);
            zn = xs[c3] + hdt * (acc + bias3);
            if (r3 == 0) zgb[c3] = zn;
            bbar(slots, g, ++phase);        // z complete
        }
        // record states at grid index m = t+1 (each WG writes its 16 z cols)
        const int m = t + 1;
        while (lp < 128 && sidx_sh[lp] == m) {
            if (r3 == 0) outb[2 + (size_t)lp * 128 + c3] = zn;
            ++lp;
        }
    }
    // epilogue: scores (g==0; zgb fresh after final barrier's acquire)
    if (g == 0 && tid < 128) {
        int lane = tid & 63;
        const int item = (tid < 64) ? pos[batch] : neg[batch];
        const float* ev = emb + (size_t)item * 128;
        float sacc = zgb[lane] * ev[lane] + zgb[lane + 64] * ev[lane + 64];
        #pragma unroll
        for (int s = 1; s < 64; s <<= 1) sacc += __shfl_xor(sacc, s, 64);
        if (lane == 0) outb[(tid < 64) ? 0 : 1] = sacc;
    }
}

extern "C" void kernel_launch(void* const* d_in, const int* in_sizes, int n_in,
                              void* d_out, int out_size, void* d_ws, size_t ws_size,
                              hipStream_t stream) {
    const float* emb   = (const float*)d_in[0];
    const float* w1    = (const float*)d_in[1];
    const float* b1    = (const float*)d_in[2];
    const float* w2    = (const float*)d_in[3];
    const float* b2    = (const float*)d_in[4];
    const float* usert = (const float*)d_in[5];
    const float* vw1   = (const float*)d_in[6];
    const float* vb1   = (const float*)d_in[7];
    const float* vw2   = (const float*)d_in[8];
    const float* vb2   = (const float*)d_in[9];
    const float* vw3   = (const float*)d_in[10];
    const float* vb3   = (const float*)d_in[11];
    const int*   u     = (const int*)d_in[12];
    const int*   hi    = (const int*)d_in[13];
    const float* ht    = (const float*)d_in[14];
    const int*   hl    = (const int*)d_in[15];
    const int*   pos   = (const int*)d_in[16];
    const int*   neg   = (const int*)d_in[17];
    const float* pt    = (const float*)d_in[18];

    int D = in_sizes[2];         // 128
    int B = in_sizes[12];        // 4
    int L = in_sizes[13] / B;    // 128

    // workspace carve-up (barrier region first, 16B-aligned buffers after)
    int*   barws    = (int*)d_ws;                           // 4 batches x 128 B slots
    float* zgbuf    = (float*)((char*)d_ws + 4096);         // B*128
    float* h1g      = zgbuf + 512;                          // B*512
    float* h2g      = h1g + 2048;                           // B*512
    float* enc      = h2g + 2048;                           // B*L*D
    float* envsb    = enc + (size_t)B * L * D;              // B*MAX_SEG*D
    float* dt_sched = envsb + (size_t)B * MAX_SEG * D;      // B*MAX_T
    int*   envid    = (int*)(dt_sched + (size_t)B * MAX_T); // B*MAX_T
    int*   stateidx = envid + (size_t)B * MAX_T;            // B*L
    int*   Tcnt     = stateidx + (size_t)B * L;             // B

    hipMemsetAsync(barws, 0, 4096, stream);
    encode_kernel<<<B * L, D, 0, stream>>>(emb, hi, w1, b1, w2, b2, enc, (float*)d_out, B, L, D);
    plan_kernel<<<B, 64, 0, stream>>>(enc, ht, hl, pt, envsb, dt_sched, envid, stateidx, Tcnt, B, L, D);
    ode_coop<<<8 * NWGB, 512, 0, stream>>>(usert, u, vw1, vb1, vw2, vb2, vw3, vb3, emb, pos, neg,
                                           envsb, dt_sched, envid, stateidx, Tcnt,
                                           zgbuf, h1g, h2g, barws, (float*)d_out, B);
}

// Round 5
// 2750.551 us; speedup vs baseline: 1.1895x; 1.1895x over previous
//
#include <hip/hip_runtime.h>
#include <math.h>

#define W_WIN 5
#define NSUB 2
#define MAX_SEG 64
#define MAX_T 256
#define NWGB 8          // workgroups per batch (ODE)

__device__ __forceinline__ float softplusf(float v) {
    // jax.nn.softplus == logaddexp(v, 0) == max(v,0) + log1p(exp(-|v|))
    return fmaxf(v, 0.0f) + log1pf(expf(-fabsf(v)));
}

// ---------------- wave-level numpy-faithful reductions (plan kernel) ----------------
__device__ __forceinline__ float npsum128(float e0, float e1) {
    int lane = threadIdx.x & 63;
    int k = lane & 7;
    float r = __shfl(e0, k, 64);
    #pragma unroll
    for (int m = 1; m < 8; ++m) r += __shfl(e0, k + 8 * m, 64);
    #pragma unroll
    for (int m = 0; m < 8; ++m) r += __shfl(e1, k + 8 * m, 64);
    float r0 = __shfl(r, 0, 64), r1 = __shfl(r, 1, 64), r2 = __shfl(r, 2, 64), r3 = __shfl(r, 3, 64);
    float r4 = __shfl(r, 4, 64), r5 = __shfl(r, 5, 64), r6 = __shfl(r, 6, 64), r7 = __shfl(r, 7, 64);
    return ((r0 + r1) + (r2 + r3)) + ((r4 + r5) + (r6 + r7));
}

__device__ __forceinline__ float wmax128(float e0, float e1) {
    float m = fmaxf(e0, e1);
    #pragma unroll
    for (int s = 1; s < 64; s <<= 1) m = fmaxf(m, __shfl_xor(m, s, 64));
    return m;
}

// ---------------- kernel 1: encoder (also writes traj_t output block) ----------------
__global__ void encode_kernel(const float* __restrict__ emb, const int* __restrict__ hi,
                              const float* __restrict__ w1, const float* __restrict__ b1,
                              const float* __restrict__ w2, const float* __restrict__ b2,
                              float* __restrict__ enc, float* __restrict__ out,
                              int B, int L, int D) {
    __shared__ float x[128];
    __shared__ float h[128];
    int row = blockIdx.x;           // 0 .. B*L-1
    int j = threadIdx.x;            // 0 .. D-1
    int idx = hi[row];
    x[j] = emb[(size_t)idx * D + j];
    __syncthreads();
    float s = b1[j];
    #pragma unroll 8
    for (int i = 0; i < 128; ++i) s += x[i] * w1[i * 128 + j];
    h[j] = fmaxf(s, 0.0f);
    __syncthreads();
    float o = b2[j];
    #pragma unroll 8
    for (int i = 0; i < 128; ++i) o += h[i] * w2[i * 128 + j];
    enc[(size_t)row * D + j] = o;
    int b = row / L, l = row % L;
    size_t OS = 2 + 2 * (size_t)L * D;
    out[(size_t)b * OS + 2 + (size_t)L * D + (size_t)l * D + j] = o;
}

// ---------------- kernel 2: APT partition + plan building (1 wave / batch) ----------------
__global__ __launch_bounds__(64) void plan_kernel(
        const float* __restrict__ enc_all, const float* __restrict__ ht,
        const int* __restrict__ hl, const float* __restrict__ pt,
        float* __restrict__ envs, float* __restrict__ dt_sched,
        int* __restrict__ envid, int* __restrict__ stateidx,
        int* __restrict__ Tcnt, int B, int L, int D) {
    const int b = blockIdx.x;
    const int lane = threadIdx.x;   // 0..63
    const float* encg = enc_all + (size_t)b * L * D;
    const float* times = ht + (size_t)b * L;

    __shared__ float encs[128 * 128];
    __shared__ double cand[160];
    __shared__ double bounds[40];
    __shared__ int starts[40];
    __shared__ int seg_s[40], seg_e[40];
    __shared__ int m_sh;

    for (int v = lane; v < 128 * 128 / 4; v += 64)
        ((float4*)encs)[v] = ((const float4*)encg)[v];
    int n = hl[b];
    __syncthreads();

    int nb = 1, ns = 1;             // uniform across the wave
    if (lane == 0) { bounds[0] = (double)times[0]; starts[0] = 0; }
    __syncthreads();

    if (n >= 2 * W_WIN) {
        int j = 0;
        while (j <= n - 2 * W_WIN) {
            const float* r = encs + j * 128;
            float ml0 = (((( r[lane]        + r[128 + lane]) + r[256 + lane]) + r[384 + lane]) + r[512 + lane]) / 5.0f;
            float ml1 = (((( r[64 + lane]   + r[192 + lane]) + r[320 + lane]) + r[448 + lane]) + r[576 + lane]) / 5.0f;
            float mr0 = (((( r[640 + lane]  + r[768 + lane]) + r[896 + lane]) + r[1024 + lane]) + r[1152 + lane]) / 5.0f;
            float mr1 = (((( r[704 + lane]  + r[832 + lane]) + r[960 + lane]) + r[1088 + lane]) + r[1216 + lane]) / 5.0f;
            float mxl = wmax128(ml0, ml1), mxr = wmax128(mr0, mr1);
            float a0 = expf(ml0 - mxl), a1 = expf(ml1 - mxl);
            float c0 = expf(mr0 - mxr), c1 = expf(mr1 - mxr);
            float sl = npsum128(a0, a1), sr = npsum128(c0, c1);
            float p0 = a0 / sl + 1e-8f, p1 = a1 / sl + 1e-8f;
            float q0 = c0 / sr + 1e-8f, q1 = c1 / sr + 1e-8f;
            float sp = npsum128(p0, p1), sq = npsum128(q0, q1);
            p0 /= sp; p1 /= sp; q0 /= sq; q1 /= sq;
            float mv0 = 0.5f * (p0 + q0), mv1 = 0.5f * (p1 + q1);
            float t10 = p0 * logf(p0 / mv0), t11 = p1 * logf(p1 / mv1);
            float t20 = q0 * logf(q0 / mv0), t21 = q1 * logf(q1 / mv1);
            float s1 = npsum128(t10, t11), s2 = npsum128(t20, t21);
            float jsd = 0.5f * s1 + 0.5f * s2;
            if (jsd > 0.5f) {
                if (nb < 39 && ns < 39) {
                    if (lane == 0) {
                        bounds[nb] = ((double)times[j + W_WIN - 1] + (double)times[j + W_WIN]) * 0.5;
                        starts[ns] = j + W_WIN;
                    }
                    nb++; ns++;
                }
                j += W_WIN;
            } else {
                j += 1;
            }
        }
    }
    __syncthreads();

    {
        double lastb = bounds[nb - 1];
        if ((double)times[n - 1] > lastb) {
            if (lane == 0) bounds[nb] = (double)times[n - 1];
            nb++;
        }
    }
    if (lane == 0) {
        for (int si = 0; si < ns; ++si) {
            seg_s[si] = starts[si];
            seg_e[si] = (si + 1 < ns) ? (starts[si + 1] - 1) : (n - 1);
        }
    }
    __syncthreads();

    int C = 0;
    for (int si = 0; si < ns; ++si) {
        int s = seg_s[si], e = seg_e[si];
        if (lane == 0) {
            double t0 = bounds[si];
            double t1 = (si + 1 < nb) ? bounds[si + 1] : bounds[nb - 1];
            int m = 0;
            cand[m++] = t0;
            for (int l = s; l <= e; ++l) {
                double tv = (double)times[l];
                if (tv < t0 || tv > t1) continue;
                if (tv != cand[m - 1]) cand[m++] = tv;
            }
            if (t1 > cand[m - 1]) cand[m++] = t1;
            for (int k = 1; k < m; ++k)
                if (cand[k] - cand[k - 1] < 1e-6) cand[k] = cand[k - 1] + 1e-6;
            m_sh = m;
        }
        __syncthreads();
        int m = m_sh;
        int K = m - 1;
        if (C + K > MAX_T) K = MAX_T - C;
        for (int k = lane; k < K; k += 64) {
            dt_sched[b * MAX_T + C + k] = (float)(cand[k + 1] - cand[k]);
            envid[b * MAX_T + C + k] = si;
        }
        for (int l = s + lane; l <= e; l += 64) {
            double tv = (double)times[l];
            int best = 0;
            double bd = fabs(cand[0] - tv);
            for (int k = 1; k < m; ++k) {
                double dk = fabs(cand[k] - tv);
                if (dk < bd) { bd = dk; best = k; }
            }
            stateidx[b * L + l] = C + best;
        }
        __syncthreads();
        C += K;
    }

    if (lane == 0) {
        double ptv = (double)pt[b];
        if (ptv > bounds[nb - 1] + 1e-6 && C < MAX_T) {
            double a0d = bounds[nb - 1], a1d = ptv;
            if (a1d - a0d < 1e-6) a1d = a0d + 1e-6;
            dt_sched[b * MAX_T + C] = (float)(a1d - a0d);
            envid[b * MAX_T + C] = ns - 1;
            C++;
        }
        Tcnt[b] = C;
    }
    for (int si = 0; si < ns; ++si) {
        int s = seg_s[si], e = seg_e[si];
        float s0 = 0.0f, s1 = 0.0f;
        for (int l = s; l <= e; ++l) {
            s0 += encs[l * 128 + lane];
            s1 += encs[l * 128 + lane + 64];
        }
        float inv = 1.0f / (float)(e - s + 1);
        envs[((size_t)b * MAX_SEG + si) * 128 + lane] = s0 * inv;
        envs[((size_t)b * MAX_SEG + si) * 128 + lane + 64] = s1 * inv;
    }
}

// ---------------- stamped-word dataflow helpers ----------------
// 8-byte aligned atomic load/store of {value, phase}: the stamp travels WITH
// the data, so no fences are needed. Overwrite distance (2 phases) exceeds
// consume distance (1 phase) by dataflow, so stamps never skip a waiter.
typedef unsigned long long u64;
__device__ __forceinline__ void publish(u64* slot, float v, int phase) {
    u64 pk = ((u64)(unsigned)phase << 32) | (u64)__float_as_uint(v);
    __hip_atomic_store(slot, pk, __ATOMIC_RELAXED, __HIP_MEMORY_SCOPE_AGENT);
}
__device__ __forceinline__ float consume(const u64* slot, int phase) {
    for (;;) {
        u64 pk = __hip_atomic_load(slot, __ATOMIC_RELAXED, __HIP_MEMORY_SCOPE_AGENT);
        if ((int)(pk >> 32) == phase) return __uint_as_float((unsigned)pk);
        __builtin_amdgcn_s_sleep(1);
    }
}

// ---------------- kernel 3: per-batch cooperative ODE, stamped dataflow ----------------
// grid = 8*NWGB blocks x 512 thr. batch = blockIdx%8 (same-XCD heuristic), g = blockIdx/8.
// WG g owns h1/h2 cols [g*64,g*64+64). Layer 3 is computed fully REDUNDANTLY in
// every WG (w3 register-resident) so z never crosses workgroups.
__global__ __launch_bounds__(512, 1) void ode_coop(
    const float* __restrict__ usert, const int* __restrict__ u,
    const float* __restrict__ vw1, const float* __restrict__ vb1,
    const float* __restrict__ vw2, const float* __restrict__ vb2,
    const float* __restrict__ vw3, const float* __restrict__ vb3,
    const float* __restrict__ emb, const int* __restrict__ pos, const int* __restrict__ neg,
    const float* __restrict__ envs, const float* __restrict__ dtsch,
    const int* __restrict__ envid, const int* __restrict__ stidx,
    const int* __restrict__ Tc,
    u64* h1st, u64* h2st,
    float* out, int B)
{
    const int batch = blockIdx.x & 7;
    if (batch >= B) return;
    const int g = blockIdx.x >> 3;      // 0..7
    const int tid = threadIdx.x;        // 0..511

    // L1/L2 mapping: cl = col-in-slice (0..63), q = input-eighth (0..7)
    const int cl = tid >> 3, q = tid & 7;
    const int c12 = g * 64 + cl;
    // L3 mapping (redundant, full): c3 = z col (0..127), r = input-quarter (0..3)
    const int c3 = tid >> 2, r = tid & 3;

    __shared__ float xs[256];           // [z | env]
    __shared__ float h1s[512];
    __shared__ float h2s[512];
    __shared__ int sidx_sh[128];
    __shared__ float dts_sh[MAX_T];
    __shared__ int sid_sh[MAX_T];

    // ---- preload weight slices into registers, skewed order (static indices!) ----
    float w1r[32], w2r[64], w3r[128];
    #pragma unroll
    for (int k4 = 0; k4 < 8; ++k4) {
        int jj = ((k4 + q) & 7) * 4;
        #pragma unroll
        for (int m = 0; m < 4; ++m)
            w1r[k4 * 4 + m] = vw1[(size_t)(q * 32 + jj + m) * 512 + c12];
    }
    #pragma unroll
    for (int k4 = 0; k4 < 16; ++k4) {
        int jj = ((k4 + 2 * q) & 15) * 4;
        #pragma unroll
        for (int m = 0; m < 4; ++m)
            w2r[k4 * 4 + m] = vw2[(size_t)(q * 64 + jj + m) * 512 + c12];
    }
    #pragma unroll
    for (int j = 0; j < 128; ++j)
        w3r[j] = vw3[(size_t)(r * 128 + j) * 128 + c3];
    const float bias1 = vb1[c12];
    const float bias2 = vb2[c12];
    const float bias3 = vb3[c3];

    if (g == 0 && tid < 128) sidx_sh[tid] = stidx[batch * 128 + tid];
    if (tid < MAX_T) {
        dts_sh[tid] = dtsch[batch * MAX_T + tid];
        sid_sh[tid] = envid[batch * MAX_T + tid];
    }

    const int T = Tc[batch];
    u64* h1b = h1st + batch * 512;
    u64* h2b = h2st + batch * 512;
    const size_t OS = 2 + 2 * (size_t)128 * 128;
    float* outb = out + (size_t)batch * OS;

    // init z into LDS (every WG loads it — no exchange needed)
    if (tid < 128) xs[tid] = usert[(size_t)u[batch] * 128 + tid];
    __syncthreads();

    // m=0 records (g==0 only)
    int lp = 0;
    if (g == 0) {
        while (lp < 128 && sidx_sh[lp] == 0) {
            if (tid < 128) outb[2 + (size_t)lp * 128 + tid] = xs[tid];
            ++lp;
        }
    }

    int phase = 0;
    for (int t = 0; t < T; ++t) {
        const int si = sid_sh[t];
        const float hdt = dts_sh[t] * 0.5f;                     // dt / NSUB
        const float* envp = envs + ((size_t)batch * MAX_SEG + si) * 128;
        if (tid >= 128 && tid < 256) xs[tid] = envp[tid - 128];
        __syncthreads();
        #pragma unroll
        for (int sub = 0; sub < NSUB; ++sub) {
            ++phase;
            // ---- layer 1: 256 -> 512, partials over q, reduce 8 lanes ----
            float acc = 0.0f;
            #pragma unroll
            for (int k4 = 0; k4 < 8; ++k4) {
                int off = q * 32 + ((k4 + q) & 7) * 4;
                float4 xv = *(const float4*)(xs + off);
                acc += w1r[k4 * 4 + 0] * xv.x + w1r[k4 * 4 + 1] * xv.y
                     + w1r[k4 * 4 + 2] * xv.z + w1r[k4 * 4 + 3] * xv.w;
            }
            #pragma unroll
            for (int s = 1; s < 8; s <<= 1) acc += __shfl_xor(acc, s, 64);
            if (q == 0) publish(&h1b[c12], softplusf(acc + bias1), phase);
            // consume h1 (each thread waits on exactly its own stamped word)
            h1s[tid] = consume(&h1b[tid], phase);
            __syncthreads();
            // ---- layer 2: 512 -> 512 ----
            acc = 0.0f;
            #pragma unroll
            for (int k4 = 0; k4 < 16; ++k4) {
                int off = q * 64 + ((k4 + 2 * q) & 15) * 4;
                float4 xv = *(const float4*)(h1s + off);
                acc += w2r[k4 * 4 + 0] * xv.x + w2r[k4 * 4 + 1] * xv.y
                     + w2r[k4 * 4 + 2] * xv.z + w2r[k4 * 4 + 3] * xv.w;
            }
            #pragma unroll
            for (int s = 1; s < 8; s <<= 1) acc += __shfl_xor(acc, s, 64);
            if (q == 0) publish(&h2b[c12], softplusf(acc + bias2), phase);
            h2s[tid] = consume(&h2b[tid], phase);
            __syncthreads();
            // ---- layer 3: 512 -> 128, fully redundant, 4 lanes per col ----
            acc = 0.0f;
            #pragma unroll
            for (int k4 = 0; k4 < 32; ++k4) {
                float4 xv = *(const float4*)(h2s + r * 128 + k4 * 4);
                acc += w3r[k4 * 4 + 0] * xv.x + w3r[k4 * 4 + 1] * xv.y
                     + w3r[k4 * 4 + 2] * xv.z + w3r[k4 * 4 + 3] * xv.w;
            }
            acc += __shfl_xor(acc, 1, 64);
            acc += __shfl_xor(acc, 2, 64);
            if (r == 0) xs[c3] = xs[c3] + hdt * (acc + bias3);
            __syncthreads();
        }
        // record states at grid index m = t+1 (g==0 writes full rows from xs)
        if (g == 0) {
            const int m = t + 1;
            while (lp < 128 && sidx_sh[lp] == m) {
                if (tid < 128) outb[2 + (size_t)lp * 128 + tid] = xs[tid];
                ++lp;
            }
        }
    }
    // epilogue: scores (g==0; final z in xs)
    if (g == 0 && tid < 128) {
        int lane = tid & 63;
        const int item = (tid < 64) ? pos[batch] : neg[batch];
        const float* ev = emb + (size_t)item * 128;
        float sacc = xs[lane] * ev[lane] + xs[lane + 64] * ev[lane + 64];
        #pragma unroll
        for (int s = 1; s < 64; s <<= 1) sacc += __shfl_xor(sacc, s, 64);
        if (lane == 0) outb[(tid < 64) ? 0 : 1] = sacc;
    }
}

extern "C" void kernel_launch(void* const* d_in, const int* in_sizes, int n_in,
                              void* d_out, int out_size, void* d_ws, size_t ws_size,
                              hipStream_t stream) {
    const float* emb   = (const float*)d_in[0];
    const float* w1    = (const float*)d_in[1];
    const float* b1    = (const float*)d_in[2];
    const float* w2    = (const float*)d_in[3];
    const float* b2    = (const float*)d_in[4];
    const float* usert = (const float*)d_in[5];
    const float* vw1   = (const float*)d_in[6];
    const float* vb1   = (const float*)d_in[7];
    const float* vw2   = (const float*)d_in[8];
    const float* vb2   = (const float*)d_in[9];
    const float* vw3   = (const float*)d_in[10];
    const float* vb3   = (const float*)d_in[11];
    const int*   u     = (const int*)d_in[12];
    const int*   hi    = (const int*)d_in[13];
    const float* ht    = (const float*)d_in[14];
    const int*   hl    = (const int*)d_in[15];
    const int*   pos   = (const int*)d_in[16];
    const int*   neg   = (const int*)d_in[17];
    const float* pt    = (const float*)d_in[18];

    int D = in_sizes[2];         // 128
    int B = in_sizes[12];        // 4
    int L = in_sizes[13] / B;    // 128

    // workspace carve-up: stamped exchange buffers first (64-bit aligned)
    u64*   h1st     = (u64*)d_ws;                           // 4*512 stamped words
    u64*   h2st     = h1st + 4 * 512;                       // 4*512
    float* enc      = (float*)(h2st + 4 * 512);             // B*L*D
    float* envsb    = enc + (size_t)B * L * D;              // B*MAX_SEG*D
    float* dt_sched = envsb + (size_t)B * MAX_SEG * D;      // B*MAX_T
    int*   envid    = (int*)(dt_sched + (size_t)B * MAX_T); // B*MAX_T
    int*   stateidx = envid + (size_t)B * MAX_T;            // B*L
    int*   Tcnt     = stateidx + (size_t)B * L;             // B

    hipMemsetAsync(h1st, 0, 4 * 512 * 2 * sizeof(u64), stream);   // stamp 0 != any phase>=1
    encode_kernel<<<B * L, D, 0, stream>>>(emb, hi, w1, b1, w2, b2, enc, (float*)d_out, B, L, D);
    plan_kernel<<<B, 64, 0, stream>>>(enc, ht, hl, pt, envsb, dt_sched, envid, stateidx, Tcnt, B, L, D);
    ode_coop<<<8 * NWGB, 512, 0, stream>>>(usert, u, vw1, vb1, vw2, vb2, vw3, vb3, emb, pos, neg,
                                           envsb, dt_sched, envid, stateidx, Tcnt,
                                           h1st, h2st, (float*)d_out, B);
}

// Round 6
// 1677.169 us; speedup vs baseline: 1.9508x; 1.6400x over previous
//
#include <hip/hip_runtime.h>
#include <math.h>

#define W_WIN 5
#define NSUB 2
#define MAX_SEG 64
#define MAX_T 256
#define NWGB 8          // workgroups per batch (ODE)

__device__ __forceinline__ float softplusf(float v) {
    // jax.nn.softplus == logaddexp(v, 0) == max(v,0) + log1p(exp(-|v|))
    return fmaxf(v, 0.0f) + log1pf(expf(-fabsf(v)));
}

// ---------------- wave-level numpy-faithful reductions ----------------
// lane l holds e0 = a[l], e1 = a[l+64]. numpy pairwise sum for n=128:
// r_k = serial fold a[k]+a[k+8]+...+a[k+120]; then ((r0+r1)+(r2+r3))+((r4+r5)+(r6+r7)).
__device__ __forceinline__ float npsum128(float e0, float e1) {
    int lane = threadIdx.x & 63;
    int k = lane & 7;
    float r = __shfl(e0, k, 64);
    #pragma unroll
    for (int m = 1; m < 8; ++m) r += __shfl(e0, k + 8 * m, 64);
    #pragma unroll
    for (int m = 0; m < 8; ++m) r += __shfl(e1, k + 8 * m, 64);
    float r0 = __shfl(r, 0, 64), r1 = __shfl(r, 1, 64), r2 = __shfl(r, 2, 64), r3 = __shfl(r, 3, 64);
    float r4 = __shfl(r, 4, 64), r5 = __shfl(r, 5, 64), r6 = __shfl(r, 6, 64), r7 = __shfl(r, 7, 64);
    return ((r0 + r1) + (r2 + r3)) + ((r4 + r5) + (r6 + r7));
}

__device__ __forceinline__ float wmax128(float e0, float e1) {
    float m = fmaxf(e0, e1);
    #pragma unroll
    for (int s = 1; s < 64; s <<= 1) m = fmaxf(m, __shfl_xor(m, s, 64));
    return m;
}

// ---------------- kernel 1: encoder (also writes traj_t output block) ----------------
__global__ void encode_kernel(const float* __restrict__ emb, const int* __restrict__ hi,
                              const float* __restrict__ w1, const float* __restrict__ b1,
                              const float* __restrict__ w2, const float* __restrict__ b2,
                              float* __restrict__ enc, float* __restrict__ out,
                              int B, int L, int D) {
    __shared__ float x[128];
    __shared__ float h[128];
    int row = blockIdx.x;           // 0 .. B*L-1
    int j = threadIdx.x;            // 0 .. D-1
    int idx = hi[row];
    x[j] = emb[(size_t)idx * D + j];
    __syncthreads();
    float s = b1[j];
    #pragma unroll 8
    for (int i = 0; i < 128; ++i) s += x[i] * w1[i * 128 + j];
    h[j] = fmaxf(s, 0.0f);
    __syncthreads();
    float o = b2[j];
    #pragma unroll 8
    for (int i = 0; i < 128; ++i) o += h[i] * w2[i * 128 + j];
    enc[(size_t)row * D + j] = o;
    int b = row / L, l = row % L;
    size_t OS = 2 + 2 * (size_t)L * D;
    out[(size_t)b * OS + 2 + (size_t)L * D + (size_t)l * D + j] = o;
}

// ---------------- kernel 1b: all window JSDs in parallel (1 wave / position) ----------------
// Bit-identical math/order to the former serial scan body; the scan itself only
// READS jsd[j], so precomputing all j is safe and removes ~120 serial iterations.
__global__ __launch_bounds__(64) void jsd_kernel(
        const float* __restrict__ enc_all, const int* __restrict__ hl,
        float* __restrict__ jsdv, int L, int D) {
    const int b = blockIdx.x >> 7;
    const int j = blockIdx.x & 127;
    const int n = hl[b];
    if (n < 2 * W_WIN || j > n - 2 * W_WIN) return;
    const int lane = threadIdx.x;
    const float* r = enc_all + ((size_t)b * L + j) * D;
    float ml0 = ((((r[lane]       + r[128 + lane]) + r[256 + lane]) + r[384 + lane]) + r[512 + lane]) / 5.0f;
    float ml1 = ((((r[64 + lane]  + r[192 + lane]) + r[320 + lane]) + r[448 + lane]) + r[576 + lane]) / 5.0f;
    float mr0 = ((((r[640 + lane] + r[768 + lane]) + r[896 + lane]) + r[1024 + lane]) + r[1152 + lane]) / 5.0f;
    float mr1 = ((((r[704 + lane] + r[832 + lane]) + r[960 + lane]) + r[1088 + lane]) + r[1216 + lane]) / 5.0f;
    float mxl = wmax128(ml0, ml1), mxr = wmax128(mr0, mr1);
    float a0 = expf(ml0 - mxl), a1 = expf(ml1 - mxl);
    float c0 = expf(mr0 - mxr), c1 = expf(mr1 - mxr);
    float sl = npsum128(a0, a1), sr = npsum128(c0, c1);
    float p0 = a0 / sl + 1e-8f, p1 = a1 / sl + 1e-8f;
    float q0 = c0 / sr + 1e-8f, q1 = c1 / sr + 1e-8f;
    float sp = npsum128(p0, p1), sq = npsum128(q0, q1);
    p0 /= sp; p1 /= sp; q0 /= sq; q1 /= sq;
    float mv0 = 0.5f * (p0 + q0), mv1 = 0.5f * (p1 + q1);
    float t10 = p0 * logf(p0 / mv0), t11 = p1 * logf(p1 / mv1);
    float t20 = q0 * logf(q0 / mv0), t21 = q1 * logf(q1 / mv1);
    float s1 = npsum128(t10, t11), s2 = npsum128(t20, t21);
    if (lane == 0) jsdv[b * L + j] = 0.5f * s1 + 0.5f * s2;
}

// ---------------- kernel 2: plan building from precomputed JSDs (1 wave / batch) ----------------
__global__ __launch_bounds__(64) void plan_kernel(
        const float* __restrict__ enc_all, const float* __restrict__ ht,
        const int* __restrict__ hl, const float* __restrict__ pt,
        const float* __restrict__ jsdv,
        float* __restrict__ envs, float* __restrict__ dt_sched,
        int* __restrict__ envid, int* __restrict__ stateidx,
        int* __restrict__ Tcnt, int B, int L, int D) {
    const int b = blockIdx.x;
    const int lane = threadIdx.x;   // 0..63
    const float* encg = enc_all + (size_t)b * L * D;
    const float* times = ht + (size_t)b * L;

    __shared__ float encs[128 * 128];
    __shared__ double cand[160];
    __shared__ double bounds[40];
    __shared__ int starts[40];
    __shared__ int seg_s[40], seg_e[40];
    __shared__ int m_sh;

    for (int v = lane; v < 128 * 128 / 4; v += 64)
        ((float4*)encs)[v] = ((const float4*)encg)[v];
    int n = hl[b];
    __syncthreads();

    int nb = 1, ns = 1;             // uniform across the wave
    if (lane == 0) { bounds[0] = (double)times[0]; starts[0] = 0; }
    __syncthreads();

    if (n >= 2 * W_WIN) {
        int j = 0;
        while (j <= n - 2 * W_WIN) {
            float jsd = jsdv[b * L + j];        // uniform broadcast load
            if (jsd > 0.5f) {
                if (nb < 39 && ns < 39) {
                    if (lane == 0) {
                        bounds[nb] = ((double)times[j + W_WIN - 1] + (double)times[j + W_WIN]) * 0.5;
                        starts[ns] = j + W_WIN;
                    }
                    nb++; ns++;
                }
                j += W_WIN;
            } else {
                j += 1;
            }
        }
    }
    __syncthreads();

    {
        double lastb = bounds[nb - 1];
        if ((double)times[n - 1] > lastb) {
            if (lane == 0) bounds[nb] = (double)times[n - 1];
            nb++;
        }
    }
    if (lane == 0) {
        for (int si = 0; si < ns; ++si) {
            seg_s[si] = starts[si];
            seg_e[si] = (si + 1 < ns) ? (starts[si + 1] - 1) : (n - 1);
        }
    }
    __syncthreads();

    int C = 0;
    for (int si = 0; si < ns; ++si) {
        int s = seg_s[si], e = seg_e[si];
        if (lane == 0) {
            double t0 = bounds[si];
            double t1 = (si + 1 < nb) ? bounds[si + 1] : bounds[nb - 1];
            int m = 0;
            cand[m++] = t0;
            for (int l = s; l <= e; ++l) {
                double tv = (double)times[l];
                if (tv < t0 || tv > t1) continue;
                if (tv != cand[m - 1]) cand[m++] = tv;
            }
            if (t1 > cand[m - 1]) cand[m++] = t1;
            for (int k = 1; k < m; ++k)
                if (cand[k] - cand[k - 1] < 1e-6) cand[k] = cand[k - 1] + 1e-6;
            m_sh = m;
        }
        __syncthreads();
        int m = m_sh;
        int K = m - 1;
        if (C + K > MAX_T) K = MAX_T - C;
        for (int k = lane; k < K; k += 64) {
            dt_sched[b * MAX_T + C + k] = (float)(cand[k + 1] - cand[k]);
            envid[b * MAX_T + C + k] = si;
        }
        for (int l = s + lane; l <= e; l += 64) {
            double tv = (double)times[l];
            int best = 0;
            double bd = fabs(cand[0] - tv);
            for (int k = 1; k < m; ++k) {
                double dk = fabs(cand[k] - tv);
                if (dk < bd) { bd = dk; best = k; }
            }
            stateidx[b * L + l] = C + best;
        }
        __syncthreads();
        C += K;
    }

    if (lane == 0) {
        double ptv = (double)pt[b];
        if (ptv > bounds[nb - 1] + 1e-6 && C < MAX_T) {
            double a0d = bounds[nb - 1], a1d = ptv;
            if (a1d - a0d < 1e-6) a1d = a0d + 1e-6;
            dt_sched[b * MAX_T + C] = (float)(a1d - a0d);
            envid[b * MAX_T + C] = ns - 1;
            C++;
        }
        Tcnt[b] = C;
    }
    for (int si = 0; si < ns; ++si) {
        int s = seg_s[si], e = seg_e[si];
        float s0 = 0.0f, s1 = 0.0f;
        for (int l = s; l <= e; ++l) {
            s0 += encs[l * 128 + lane];
            s1 += encs[l * 128 + lane + 64];
        }
        float inv = 1.0f / (float)(e - s + 1);
        envs[((size_t)b * MAX_SEG + si) * 128 + lane] = s0 * inv;
        envs[((size_t)b * MAX_SEG + si) * 128 + lane + 64] = s1 * inv;
    }
}

// ---------------- kernel 3: per-batch cooperative ODE, O(1)-poll stamp exchange ----------------
// grid = 8*NWGB blocks x 512 thr. batch = blockIdx%8 (same-XCD heuristic; correctness
// is placement-independent via agent scope), g = blockIdx/8. WG g owns h1/h2 cols
// [g*64,g*64+64) and z cols [g*16,g*16+16). Exchange protocol per edge:
//   producers store values (relaxed agent atomics) -> __syncthreads (drains vmcnt
//   per wave before s_barrier) -> tid0 release-stores stamp[g] -> tids 0..7 poll the
//   8 stamps (relaxed) -> __syncthreads -> all threads single-shot relaxed-load values
//   (agent atomics bypass L1, so no fences/invalidate needed anywhere).
// Overwrite safety: producer of phase p+1 transitively depends on every WG having
// consumed phase p (h1(p+1) needs z(p), z(p) needs h2(p), h2(p) needs h1(p)).
__global__ __launch_bounds__(512, 1) void ode_coop(
    const float* __restrict__ usert, const int* __restrict__ u,
    const float* __restrict__ vw1, const float* __restrict__ vb1,
    const float* __restrict__ vw2, const float* __restrict__ vb2,
    const float* __restrict__ vw3, const float* __restrict__ vb3,
    const float* __restrict__ emb, const int* __restrict__ pos, const int* __restrict__ neg,
    const float* __restrict__ envs, const float* __restrict__ dtsch,
    const int* __restrict__ envid, const int* __restrict__ stidx,
    const int* __restrict__ Tc,
    float* zg, float* h1g, float* h2g, int* barws,
    float* out, int B)
{
    const int batch = blockIdx.x & 7;
    if (batch >= B) return;
    const int g = blockIdx.x >> 3;      // 0..7
    const int tid = threadIdx.x;        // 0..511

    // L1/L2 mapping: cl = col-in-slice (0..63), q = input-eighth (0..7)
    const int cl = tid >> 3, q = tid & 7;
    const int c12 = g * 64 + cl;
    // L3 mapping: c3l = col-in-slice (0..15), r3 = input-range (0..31)
    const int c3l = tid >> 5, r3 = tid & 31;
    const int c3 = g * 16 + c3l;

    __shared__ float xs[256];           // [z | env]
    __shared__ float h1s[512];
    __shared__ float h2s[512];
    __shared__ int sidx_sh[128];
    __shared__ float dts_sh[MAX_T];
    __shared__ int sid_sh[MAX_T];

    // ---- preload weight slices into registers, skewed order (static indices) ----
    float w1r[32], w2r[64], w3r[16];
    #pragma unroll
    for (int k4 = 0; k4 < 8; ++k4) {
        int jj = ((k4 + q) & 7) * 4;
        #pragma unroll
        for (int m = 0; m < 4; ++m)
            w1r[k4 * 4 + m] = vw1[(size_t)(q * 32 + jj + m) * 512 + c12];
    }
    #pragma unroll
    for (int k4 = 0; k4 < 16; ++k4) {
        int jj = ((k4 + 2 * q) & 15) * 4;
        #pragma unroll
        for (int m = 0; m < 4; ++m)
            w2r[k4 * 4 + m] = vw2[(size_t)(q * 64 + jj + m) * 512 + c12];
    }
    #pragma unroll
    for (int k4 = 0; k4 < 4; ++k4) {
        int jj = ((k4 + r3) & 3) * 4;
        #pragma unroll
        for (int m = 0; m < 4; ++m)
            w3r[k4 * 4 + m] = vw3[(size_t)(r3 * 16 + jj + m) * 128 + c3];
    }
    const float bias1 = vb1[c12];
    const float bias2 = vb2[c12];
    const float bias3 = vb3[c3];

    if (tid < 128) sidx_sh[tid] = stidx[batch * 128 + tid];
    if (tid < MAX_T) {
        dts_sh[tid] = dtsch[batch * MAX_T + tid];
        sid_sh[tid] = envid[batch * MAX_T + tid];
    }

    const int T = Tc[batch];
    float* zgb  = zg  + batch * 128;
    float* h1gb = h1g + batch * 512;
    float* h2gb = h2g + batch * 512;
    int* st = barws + batch * 64;       // [0..7]=h1 stamps, [8..15]=h2, [16..23]=z
    const size_t OS = 2 + 2 * (size_t)128 * 128;
    float* outb = out + (size_t)batch * OS;

    // init z into LDS (every WG loads it directly — no exchange)
    if (tid < 128) xs[tid] = usert[(size_t)u[batch] * 128 + tid];
    __syncthreads();

    // m=0 records (g==0 writes full rows)
    int lp = 0;
    if (g == 0) {
        while (lp < 128 && sidx_sh[lp] == 0) {
            if (tid < 128) outb[2 + (size_t)lp * 128 + tid] = xs[tid];
            ++lp;
        }
    }

    int phase = 0;
    for (int t = 0; t < T; ++t) {
        const int si = sid_sh[t];
        const float hdt = dts_sh[t] * 0.5f;                     // dt / NSUB
        const float* envp = envs + ((size_t)batch * MAX_SEG + si) * 128;
        if (tid >= 128 && tid < 256) xs[tid] = envp[tid - 128];
        __syncthreads();
        #pragma unroll
        for (int sub = 0; sub < NSUB; ++sub) {
            ++phase;
            // ---- layer 1: 256 -> 512, partials over q, reduce 8 lanes ----
            float acc = 0.0f;
            #pragma unroll
            for (int k4 = 0; k4 < 8; ++k4) {
                int off = q * 32 + ((k4 + q) & 7) * 4;
                float4 xv = *(const float4*)(xs + off);
                acc += w1r[k4 * 4 + 0] * xv.x + w1r[k4 * 4 + 1] * xv.y
                     + w1r[k4 * 4 + 2] * xv.z + w1r[k4 * 4 + 3] * xv.w;
            }
            #pragma unroll
            for (int s = 1; s < 8; s <<= 1) acc += __shfl_xor(acc, s, 64);
            if (q == 0)
                __hip_atomic_store(&h1gb[c12], softplusf(acc + bias1),
                                   __ATOMIC_RELAXED, __HIP_MEMORY_SCOPE_AGENT);
            __syncthreads();
            if (tid == 0)
                __hip_atomic_store(&st[g], phase, __ATOMIC_RELEASE, __HIP_MEMORY_SCOPE_AGENT);
            if (tid < NWGB)
                while (__hip_atomic_load(&st[tid], __ATOMIC_RELAXED, __HIP_MEMORY_SCOPE_AGENT) < phase)
                    __builtin_amdgcn_s_sleep(1);
            __syncthreads();
            h1s[tid] = __hip_atomic_load(&h1gb[tid], __ATOMIC_RELAXED, __HIP_MEMORY_SCOPE_AGENT);
            __syncthreads();
            // ---- layer 2: 512 -> 512 ----
            acc = 0.0f;
            #pragma unroll
            for (int k4 = 0; k4 < 16; ++k4) {
                int off = q * 64 + ((k4 + 2 * q) & 15) * 4;
                float4 xv = *(const float4*)(h1s + off);
                acc += w2r[k4 * 4 + 0] * xv.x + w2r[k4 * 4 + 1] * xv.y
                     + w2r[k4 * 4 + 2] * xv.z + w2r[k4 * 4 + 3] * xv.w;
            }
            #pragma unroll
            for (int s = 1; s < 8; s <<= 1) acc += __shfl_xor(acc, s, 64);
            if (q == 0)
                __hip_atomic_store(&h2gb[c12], softplusf(acc + bias2),
                                   __ATOMIC_RELAXED, __HIP_MEMORY_SCOPE_AGENT);
            __syncthreads();
            if (tid == 0)
                __hip_atomic_store(&st[8 + g], phase, __ATOMIC_RELEASE, __HIP_MEMORY_SCOPE_AGENT);
            if (tid < NWGB)
                while (__hip_atomic_load(&st[8 + tid], __ATOMIC_RELAXED, __HIP_MEMORY_SCOPE_AGENT) < phase)
                    __builtin_amdgcn_s_sleep(1);
            __syncthreads();
            h2s[tid] = __hip_atomic_load(&h2gb[tid], __ATOMIC_RELAXED, __HIP_MEMORY_SCOPE_AGENT);
            __syncthreads();
            // ---- layer 3: 512 -> 128 slice + Euler update ----
            acc = 0.0f;
            #pragma unroll
            for (int k4 = 0; k4 < 4; ++k4) {
                int off = r3 * 16 + ((k4 + r3) & 3) * 4;
                float4 xv = *(const float4*)(h2s + off);
                acc += w3r[k4 * 4 + 0] * xv.x + w3r[k4 * 4 + 1] * xv.y
                     + w3r[k4 * 4 + 2] * xv.z + w3r[k4 * 4 + 3] * xv.w;
            }
            #pragma unroll
            for (int s = 1; s < 32; s <<= 1) acc += __shfl_xor(acc, s, 64);
            if (r3 == 0)
                __hip_atomic_store(&zgb[c3], xs[c3] + hdt * (acc + bias3),
                                   __ATOMIC_RELAXED, __HIP_MEMORY_SCOPE_AGENT);
            __syncthreads();
            if (tid == 0)
                __hip_atomic_store(&st[16 + g], phase, __ATOMIC_RELEASE, __HIP_MEMORY_SCOPE_AGENT);
            if (tid < NWGB)
                while (__hip_atomic_load(&st[16 + tid], __ATOMIC_RELAXED, __HIP_MEMORY_SCOPE_AGENT) < phase)
                    __builtin_amdgcn_s_sleep(1);
            __syncthreads();
            if (tid < 128)
                xs[tid] = __hip_atomic_load(&zgb[tid], __ATOMIC_RELAXED, __HIP_MEMORY_SCOPE_AGENT);
            __syncthreads();
        }
        // record states at grid index m = t+1 (g==0 writes full rows from xs)
        if (g == 0) {
            const int m = t + 1;
            while (lp < 128 && sidx_sh[lp] == m) {
                if (tid < 128) outb[2 + (size_t)lp * 128 + tid] = xs[tid];
                ++lp;
            }
        }
    }
    // epilogue: scores (g==0; final z in xs)
    if (g == 0 && tid < 128) {
        int lane = tid & 63;
        const int item = (tid < 64) ? pos[batch] : neg[batch];
        const float* ev = emb + (size_t)item * 128;
        float sacc = xs[lane] * ev[lane] + xs[lane + 64] * ev[lane + 64];
        #pragma unroll
        for (int s = 1; s < 64; s <<= 1) sacc += __shfl_xor(sacc, s, 64);
        if (lane == 0) outb[(tid < 64) ? 0 : 1] = sacc;
    }
}

extern "C" void kernel_launch(void* const* d_in, const int* in_sizes, int n_in,
                              void* d_out, int out_size, void* d_ws, size_t ws_size,
                              hipStream_t stream) {
    const float* emb   = (const float*)d_in[0];
    const float* w1    = (const float*)d_in[1];
    const float* b1    = (const float*)d_in[2];
    const float* w2    = (const float*)d_in[3];
    const float* b2    = (const float*)d_in[4];
    const float* usert = (const float*)d_in[5];
    const float* vw1   = (const float*)d_in[6];
    const float* vb1   = (const float*)d_in[7];
    const float* vw2   = (const float*)d_in[8];
    const float* vb2   = (const float*)d_in[9];
    const float* vw3   = (const float*)d_in[10];
    const float* vb3   = (const float*)d_in[11];
    const int*   u     = (const int*)d_in[12];
    const int*   hi    = (const int*)d_in[13];
    const float* ht    = (const float*)d_in[14];
    const int*   hl    = (const int*)d_in[15];
    const int*   pos   = (const int*)d_in[16];
    const int*   neg   = (const int*)d_in[17];
    const float* pt    = (const float*)d_in[18];

    int D = in_sizes[2];         // 128
    int B = in_sizes[12];        // 4
    int L = in_sizes[13] / B;    // 128

    // workspace carve-up (stamp region first, value buffers after)
    int*   barws    = (int*)d_ws;                           // 4 batches x 256 B
    float* zgbuf    = (float*)((char*)d_ws + 4096);         // B*128
    float* h1g      = zgbuf + 512;                          // B*512
    float* h2g      = h1g + 2048;                           // B*512
    float* jsdv     = h2g + 2048;                           // B*L
    float* enc      = jsdv + (size_t)B * L;                 // B*L*D
    float* envsb    = enc + (size_t)B * L * D;              // B*MAX_SEG*D
    float* dt_sched = envsb + (size_t)B * MAX_SEG * D;      // B*MAX_T
    int*   envid    = (int*)(dt_sched + (size_t)B * MAX_T); // B*MAX_T
    int*   stateidx = envid + (size_t)B * MAX_T;            // B*L
    int*   Tcnt     = stateidx + (size_t)B * L;             // B

    hipMemsetAsync(barws, 0, 4096, stream);
    encode_kernel<<<B * L, D, 0, stream>>>(emb, hi, w1, b1, w2, b2, enc, (float*)d_out, B, L, D);
    jsd_kernel<<<B * 128, 64, 0, stream>>>(enc, hl, jsdv, L, D);
    plan_kernel<<<B, 64, 0, stream>>>(enc, ht, hl, pt, jsdv, envsb, dt_sched, envid, stateidx, Tcnt, B, L, D);
    ode_coop<<<8 * NWGB, 512, 0, stream>>>(usert, u, vw1, vb1, vw2, vb2, vw3, vb3, emb, pos, neg,
                                           envsb, dt_sched, envid, stateidx, Tcnt,
                                           zgbuf, h1g, h2g, barws, (float*)d_out, B);
}

// Round 7
// 1346.147 us; speedup vs baseline: 2.4306x; 1.2459x over previous
//
#include <hip/hip_runtime.h>
#include <math.h>

#define W_WIN 5
#define NSUB 2
#define MAX_SEG 64
#define MAX_T 256
#define NWGB 8          // workgroups per batch (ODE)

__device__ __forceinline__ float softplusf(float v) {
    // jax.nn.softplus == logaddexp(v, 0) == max(v,0) + log1p(exp(-|v|))
    return fmaxf(v, 0.0f) + log1pf(expf(-fabsf(v)));
}

// ---------------- wave-level numpy-faithful reductions ----------------
// lane l holds e0 = a[l], e1 = a[l+64]. numpy pairwise sum for n=128:
// r_k = serial fold a[k]+a[k+8]+...+a[k+120]; then ((r0+r1)+(r2+r3))+((r4+r5)+(r6+r7)).
__device__ __forceinline__ float npsum128(float e0, float e1) {
    int lane = threadIdx.x & 63;
    int k = lane & 7;
    float r = __shfl(e0, k, 64);
    #pragma unroll
    for (int m = 1; m < 8; ++m) r += __shfl(e0, k + 8 * m, 64);
    #pragma unroll
    for (int m = 0; m < 8; ++m) r += __shfl(e1, k + 8 * m, 64);
    float r0 = __shfl(r, 0, 64), r1 = __shfl(r, 1, 64), r2 = __shfl(r, 2, 64), r3 = __shfl(r, 3, 64);
    float r4 = __shfl(r, 4, 64), r5 = __shfl(r, 5, 64), r6 = __shfl(r, 6, 64), r7 = __shfl(r, 7, 64);
    return ((r0 + r1) + (r2 + r3)) + ((r4 + r5) + (r6 + r7));
}

__device__ __forceinline__ float wmax128(float e0, float e1) {
    float m = fmaxf(e0, e1);
    #pragma unroll
    for (int s = 1; s < 64; s <<= 1) m = fmaxf(m, __shfl_xor(m, s, 64));
    return m;
}

// ---------------- kernel 1: encoder (also writes traj_t output block) ----------------
__global__ void encode_kernel(const float* __restrict__ emb, const int* __restrict__ hi,
                              const float* __restrict__ w1, const float* __restrict__ b1,
                              const float* __restrict__ w2, const float* __restrict__ b2,
                              float* __restrict__ enc, float* __restrict__ out,
                              int B, int L, int D) {
    __shared__ float x[128];
    __shared__ float h[128];
    int row = blockIdx.x;           // 0 .. B*L-1
    int j = threadIdx.x;            // 0 .. D-1
    int idx = hi[row];
    x[j] = emb[(size_t)idx * D + j];
    __syncthreads();
    float s = b1[j];
    #pragma unroll 8
    for (int i = 0; i < 128; ++i) s += x[i] * w1[i * 128 + j];
    h[j] = fmaxf(s, 0.0f);
    __syncthreads();
    float o = b2[j];
    #pragma unroll 8
    for (int i = 0; i < 128; ++i) o += h[i] * w2[i * 128 + j];
    enc[(size_t)row * D + j] = o;
    int b = row / L, l = row % L;
    size_t OS = 2 + 2 * (size_t)L * D;
    out[(size_t)b * OS + 2 + (size_t)L * D + (size_t)l * D + j] = o;
}

// ---------------- kernel 1b: all window JSDs in parallel (1 wave / position) ----------------
__global__ __launch_bounds__(64) void jsd_kernel(
        const float* __restrict__ enc_all, const int* __restrict__ hl,
        float* __restrict__ jsdv, int L, int D) {
    const int b = blockIdx.x >> 7;
    const int j = blockIdx.x & 127;
    const int n = hl[b];
    if (n < 2 * W_WIN || j > n - 2 * W_WIN) return;
    const int lane = threadIdx.x;
    const float* r = enc_all + ((size_t)b * L + j) * D;
    float ml0 = ((((r[lane]       + r[128 + lane]) + r[256 + lane]) + r[384 + lane]) + r[512 + lane]) / 5.0f;
    float ml1 = ((((r[64 + lane]  + r[192 + lane]) + r[320 + lane]) + r[448 + lane]) + r[576 + lane]) / 5.0f;
    float mr0 = ((((r[640 + lane] + r[768 + lane]) + r[896 + lane]) + r[1024 + lane]) + r[1152 + lane]) / 5.0f;
    float mr1 = ((((r[704 + lane] + r[832 + lane]) + r[960 + lane]) + r[1088 + lane]) + r[1216 + lane]) / 5.0f;
    float mxl = wmax128(ml0, ml1), mxr = wmax128(mr0, mr1);
    float a0 = expf(ml0 - mxl), a1 = expf(ml1 - mxl);
    float c0 = expf(mr0 - mxr), c1 = expf(mr1 - mxr);
    float sl = npsum128(a0, a1), sr = npsum128(c0, c1);
    float p0 = a0 / sl + 1e-8f, p1 = a1 / sl + 1e-8f;
    float q0 = c0 / sr + 1e-8f, q1 = c1 / sr + 1e-8f;
    float sp = npsum128(p0, p1), sq = npsum128(q0, q1);
    p0 /= sp; p1 /= sp; q0 /= sq; q1 /= sq;
    float mv0 = 0.5f * (p0 + q0), mv1 = 0.5f * (p1 + q1);
    float t10 = p0 * logf(p0 / mv0), t11 = p1 * logf(p1 / mv1);
    float t20 = q0 * logf(q0 / mv0), t21 = q1 * logf(q1 / mv1);
    float s1 = npsum128(t10, t11), s2 = npsum128(t20, t21);
    if (lane == 0) jsdv[b * L + j] = 0.5f * s1 + 0.5f * s2;
}

// ---------------- kernel 2: plan building from precomputed JSDs (1 wave / batch) ----------------
__global__ __launch_bounds__(64) void plan_kernel(
        const float* __restrict__ enc_all, const float* __restrict__ ht,
        const int* __restrict__ hl, const float* __restrict__ pt,
        const float* __restrict__ jsdv,
        float* __restrict__ envs, float* __restrict__ dt_sched,
        int* __restrict__ envid, int* __restrict__ stateidx,
        int* __restrict__ Tcnt, int B, int L, int D) {
    const int b = blockIdx.x;
    const int lane = threadIdx.x;   // 0..63
    const float* encg = enc_all + (size_t)b * L * D;
    const float* times = ht + (size_t)b * L;

    __shared__ float encs[128 * 128];
    __shared__ double cand[160];
    __shared__ double bounds[40];
    __shared__ int starts[40];
    __shared__ int seg_s[40], seg_e[40];
    __shared__ int m_sh;

    for (int v = lane; v < 128 * 128 / 4; v += 64)
        ((float4*)encs)[v] = ((const float4*)encg)[v];
    int n = hl[b];
    __syncthreads();

    int nb = 1, ns = 1;             // uniform across the wave
    if (lane == 0) { bounds[0] = (double)times[0]; starts[0] = 0; }
    __syncthreads();

    if (n >= 2 * W_WIN) {
        int j = 0;
        while (j <= n - 2 * W_WIN) {
            float jsd = jsdv[b * L + j];        // uniform broadcast load
            if (jsd > 0.5f) {
                if (nb < 39 && ns < 39) {
                    if (lane == 0) {
                        bounds[nb] = ((double)times[j + W_WIN - 1] + (double)times[j + W_WIN]) * 0.5;
                        starts[ns] = j + W_WIN;
                    }
                    nb++; ns++;
                }
                j += W_WIN;
            } else {
                j += 1;
            }
        }
    }
    __syncthreads();

    {
        double lastb = bounds[nb - 1];
        if ((double)times[n - 1] > lastb) {
            if (lane == 0) bounds[nb] = (double)times[n - 1];
            nb++;
        }
    }
    if (lane == 0) {
        for (int si = 0; si < ns; ++si) {
            seg_s[si] = starts[si];
            seg_e[si] = (si + 1 < ns) ? (starts[si + 1] - 1) : (n - 1);
        }
    }
    __syncthreads();

    int C = 0;
    for (int si = 0; si < ns; ++si) {
        int s = seg_s[si], e = seg_e[si];
        if (lane == 0) {
            double t0 = bounds[si];
            double t1 = (si + 1 < nb) ? bounds[si + 1] : bounds[nb - 1];
            int m = 0;
            cand[m++] = t0;
            for (int l = s; l <= e; ++l) {
                double tv = (double)times[l];
                if (tv < t0 || tv > t1) continue;
                if (tv != cand[m - 1]) cand[m++] = tv;
            }
            if (t1 > cand[m - 1]) cand[m++] = t1;
            for (int k = 1; k < m; ++k)
                if (cand[k] - cand[k - 1] < 1e-6) cand[k] = cand[k - 1] + 1e-6;
            m_sh = m;
        }
        __syncthreads();
        int m = m_sh;
        int K = m - 1;
        if (C + K > MAX_T) K = MAX_T - C;
        for (int k = lane; k < K; k += 64) {
            dt_sched[b * MAX_T + C + k] = (float)(cand[k + 1] - cand[k]);
            envid[b * MAX_T + C + k] = si;
        }
        for (int l = s + lane; l <= e; l += 64) {
            double tv = (double)times[l];
            int best = 0;
            double bd = fabs(cand[0] - tv);
            for (int k = 1; k < m; ++k) {
                double dk = fabs(cand[k] - tv);
                if (dk < bd) { bd = dk; best = k; }
            }
            stateidx[b * L + l] = C + best;
        }
        __syncthreads();
        C += K;
    }

    if (lane == 0) {
        double ptv = (double)pt[b];
        if (ptv > bounds[nb - 1] + 1e-6 && C < MAX_T) {
            double a0d = bounds[nb - 1], a1d = ptv;
            if (a1d - a0d < 1e-6) a1d = a0d + 1e-6;
            dt_sched[b * MAX_T + C] = (float)(a1d - a0d);
            envid[b * MAX_T + C] = ns - 1;
            C++;
        }
        Tcnt[b] = C;
    }
    for (int si = 0; si < ns; ++si) {
        int s = seg_s[si], e = seg_e[si];
        float s0 = 0.0f, s1 = 0.0f;
        for (int l = s; l <= e; ++l) {
            s0 += encs[l * 128 + lane];
            s1 += encs[l * 128 + lane + 64];
        }
        float inv = 1.0f / (float)(e - s + 1);
        envs[((size_t)b * MAX_SEG + si) * 128 + lane] = s0 * inv;
        envs[((size_t)b * MAX_SEG + si) * 128 + lane + 64] = s1 * inv;
    }
}

// ---------------- stamped-word dataflow helpers ----------------
// 8-byte aligned atomic {value, phase}: the stamp travels WITH the data, so a
// single load both detects readiness and delivers the value (1 round-trip).
// Agent-scope atomics bypass L1 -> no fences needed. Overwrite distance (next
// write of a slot) transitively exceeds consume distance via the dataflow
// chain h1(p+1) <- z(p) <- zp(p) <- h2(p) <- h1(p).
typedef unsigned long long u64;
__device__ __forceinline__ void publish(u64* slot, float v, int phase) {
    u64 pk = ((u64)(unsigned)phase << 32) | (u64)__float_as_uint(v);
    __hip_atomic_store(slot, pk, __ATOMIC_RELAXED, __HIP_MEMORY_SCOPE_AGENT);
}
__device__ __forceinline__ float consume(const u64* slot, int phase) {
    for (;;) {
        u64 pk = __hip_atomic_load(slot, __ATOMIC_RELAXED, __HIP_MEMORY_SCOPE_AGENT);
        if ((int)(pk >> 32) == phase) return __uint_as_float((unsigned)pk);
        __builtin_amdgcn_s_sleep(1);
    }
}

// ---------------- kernel 3: per-batch cooperative ODE, 2 edges/substep ----------------
// grid = 8*NWGB blocks x 512 thr. batch = blockIdx%8, g = blockIdx/8.
// WG g owns h1/h2 cols [g*64,g*64+64). Layer 3 uses LINEARITY: each WG computes a
// full-width z-partial from its OWN h2 slice (h2 never leaves the WG; stays in LDS);
// consumers sum the 8 partials in fixed order g=0..7. Per substep:
//   edge A: h1 slice exchange (512 stamped words)
//   edge B: z-partial exchange (8 x 128 stamped words)
// No barrier between publish and consume: each wave publishes its own words before
// polling others (program order) -> no circular wait; stamped words self-announce.
__global__ __launch_bounds__(512, 1) void ode_coop(
    const float* __restrict__ usert, const int* __restrict__ u,
    const float* __restrict__ vw1, const float* __restrict__ vb1,
    const float* __restrict__ vw2, const float* __restrict__ vb2,
    const float* __restrict__ vw3, const float* __restrict__ vb3,
    const float* __restrict__ emb, const int* __restrict__ pos, const int* __restrict__ neg,
    const float* __restrict__ envs, const float* __restrict__ dtsch,
    const int* __restrict__ envid, const int* __restrict__ stidx,
    const int* __restrict__ Tc,
    u64* h1st, u64* zpst,
    float* out, int B)
{
    const int batch = blockIdx.x & 7;
    if (batch >= B) return;
    const int g = blockIdx.x >> 3;      // 0..7
    const int tid = threadIdx.x;        // 0..511

    // L1/L2 mapping: cl = col-in-slice (0..63), q = input-eighth (0..7)
    const int cl = tid >> 3, q = tid & 7;
    const int c12 = g * 64 + cl;
    // L3-partial mapping: cz = z col (0..127), r = slice-row-quarter (0..3)
    const int cz = tid >> 2, r = tid & 3;

    __shared__ float xs[256];           // [z | env]
    __shared__ float h1s[512];
    __shared__ float h2s[64];           // THIS WG's h2 slice only
    __shared__ int sidx_sh[128];
    __shared__ float dts_sh[MAX_T];
    __shared__ int sid_sh[MAX_T];

    // ---- preload weight slices into registers, skewed order (static indices) ----
    float w1r[32], w2r[64], w3p[16];
    #pragma unroll
    for (int k4 = 0; k4 < 8; ++k4) {
        int jj = ((k4 + q) & 7) * 4;
        #pragma unroll
        for (int m = 0; m < 4; ++m)
            w1r[k4 * 4 + m] = vw1[(size_t)(q * 32 + jj + m) * 512 + c12];
    }
    #pragma unroll
    for (int k4 = 0; k4 < 16; ++k4) {
        int jj = ((k4 + 2 * q) & 15) * 4;
        #pragma unroll
        for (int m = 0; m < 4; ++m)
            w2r[k4 * 4 + m] = vw2[(size_t)(q * 64 + jj + m) * 512 + c12];
    }
    #pragma unroll
    for (int k = 0; k < 16; ++k)
        w3p[k] = vw3[(size_t)(g * 64 + r * 16 + k) * 128 + cz];
    const float bias1 = vb1[c12];
    const float bias2 = vb2[c12];
    const float b3c = (tid < 128) ? vb3[tid] : 0.0f;

    if (tid < 128) sidx_sh[tid] = stidx[batch * 128 + tid];
    if (tid < MAX_T) {
        dts_sh[tid] = dtsch[batch * MAX_T + tid];
        sid_sh[tid] = envid[batch * MAX_T + tid];
    }

    const int T = Tc[batch];
    u64* h1b = h1st + batch * 512;
    u64* zpb = zpst + batch * 1024;
    const size_t OS = 2 + 2 * (size_t)128 * 128;
    float* outb = out + (size_t)batch * OS;

    // init z into LDS (every WG loads it directly — no exchange)
    if (tid < 128) xs[tid] = usert[(size_t)u[batch] * 128 + tid];
    __syncthreads();

    // m=0 records (g==0 writes full rows)
    int lp = 0;
    if (g == 0) {
        while (lp < 128 && sidx_sh[lp] == 0) {
            if (tid < 128) outb[2 + (size_t)lp * 128 + tid] = xs[tid];
            ++lp;
        }
    }

    int phase = 0;
    for (int t = 0; t < T; ++t) {
        const int si = sid_sh[t];
        const float hdt = dts_sh[t] * 0.5f;                     // dt / NSUB
        const float* envp = envs + ((size_t)batch * MAX_SEG + si) * 128;
        if (tid >= 128 && tid < 256) xs[tid] = envp[tid - 128];
        __syncthreads();
        #pragma unroll
        for (int sub = 0; sub < NSUB; ++sub) {
            ++phase;
            // ---- layer 1: 256 -> 512 slice, partials over q, reduce 8 lanes ----
            float acc = 0.0f;
            #pragma unroll
            for (int k4 = 0; k4 < 8; ++k4) {
                int off = q * 32 + ((k4 + q) & 7) * 4;
                float4 xv = *(const float4*)(xs + off);
                acc += w1r[k4 * 4 + 0] * xv.x + w1r[k4 * 4 + 1] * xv.y
                     + w1r[k4 * 4 + 2] * xv.z + w1r[k4 * 4 + 3] * xv.w;
            }
            #pragma unroll
            for (int s = 1; s < 8; s <<= 1) acc += __shfl_xor(acc, s, 64);
            // edge A: publish h1 slice, consume full h1 (stamped words)
            if (q == 0) publish(&h1b[c12], softplusf(acc + bias1), phase);
            h1s[tid] = consume(&h1b[tid], phase);
            __syncthreads();
            // ---- layer 2: 512 -> 64 slice (stays in LDS, no exchange) ----
            acc = 0.0f;
            #pragma unroll
            for (int k4 = 0; k4 < 16; ++k4) {
                int off = q * 64 + ((k4 + 2 * q) & 15) * 4;
                float4 xv = *(const float4*)(h1s + off);
                acc += w2r[k4 * 4 + 0] * xv.x + w2r[k4 * 4 + 1] * xv.y
                     + w2r[k4 * 4 + 2] * xv.z + w2r[k4 * 4 + 3] * xv.w;
            }
            #pragma unroll
            for (int s = 1; s < 8; s <<= 1) acc += __shfl_xor(acc, s, 64);
            if (q == 0) h2s[cl] = softplusf(acc + bias2);
            __syncthreads();
            // ---- layer 3 PARTIAL: this WG's 64 h2 rows -> full 128-wide partial ----
            float az = 0.0f;
            #pragma unroll
            for (int k4 = 0; k4 < 4; ++k4) {
                float4 hv = *(const float4*)(h2s + r * 16 + k4 * 4);
                az += w3p[k4 * 4 + 0] * hv.x + w3p[k4 * 4 + 1] * hv.y
                    + w3p[k4 * 4 + 2] * hv.z + w3p[k4 * 4 + 3] * hv.w;
            }
            az += __shfl_xor(az, 1, 64);
            az += __shfl_xor(az, 2, 64);
            // edge B: publish z-partial, consume all 8 partials (parallel poll)
            if (r == 0) publish(&zpb[g * 128 + cz], az, phase);
            if (tid < 128) {
                u64 pk[8];
                for (;;) {
                    #pragma unroll
                    for (int g2 = 0; g2 < 8; ++g2)
                        pk[g2] = __hip_atomic_load(&zpb[g2 * 128 + tid],
                                                   __ATOMIC_RELAXED, __HIP_MEMORY_SCOPE_AGENT);
                    bool ok = true;
                    #pragma unroll
                    for (int g2 = 0; g2 < 8; ++g2) ok &= ((int)(pk[g2] >> 32) == phase);
                    if (ok) break;
                    __builtin_amdgcn_s_sleep(1);
                }
                float sum = 0.0f;
                #pragma unroll
                for (int g2 = 0; g2 < 8; ++g2) sum += __uint_as_float((unsigned)pk[g2]);
                xs[tid] = xs[tid] + hdt * (sum + b3c);
            }
            __syncthreads();
        }
        // record states at grid index m = t+1 (g==0 writes full rows from xs)
        if (g == 0) {
            const int m = t + 1;
            while (lp < 128 && sidx_sh[lp] == m) {
                if (tid < 128) outb[2 + (size_t)lp * 128 + tid] = xs[tid];
                ++lp;
            }
        }
    }
    // epilogue: scores (g==0; final z in xs)
    if (g == 0 && tid < 128) {
        int lane = tid & 63;
        const int item = (tid < 64) ? pos[batch] : neg[batch];
        const float* ev = emb + (size_t)item * 128;
        float sacc = xs[lane] * ev[lane] + xs[lane + 64] * ev[lane + 64];
        #pragma unroll
        for (int s = 1; s < 64; s <<= 1) sacc += __shfl_xor(sacc, s, 64);
        if (lane == 0) outb[(tid < 64) ? 0 : 1] = sacc;
    }
}

extern "C" void kernel_launch(void* const* d_in, const int* in_sizes, int n_in,
                              void* d_out, int out_size, void* d_ws, size_t ws_size,
                              hipStream_t stream) {
    const float* emb   = (const float*)d_in[0];
    const float* w1    = (const float*)d_in[1];
    const float* b1    = (const float*)d_in[2];
    const float* w2    = (const float*)d_in[3];
    const float* b2    = (const float*)d_in[4];
    const float* usert = (const float*)d_in[5];
    const float* vw1   = (const float*)d_in[6];
    const float* vb1   = (const float*)d_in[7];
    const float* vw2   = (const float*)d_in[8];
    const float* vb2   = (const float*)d_in[9];
    const float* vw3   = (const float*)d_in[10];
    const float* vb3   = (const float*)d_in[11];
    const int*   u     = (const int*)d_in[12];
    const int*   hi    = (const int*)d_in[13];
    const float* ht    = (const float*)d_in[14];
    const int*   hl    = (const int*)d_in[15];
    const int*   pos   = (const int*)d_in[16];
    const int*   neg   = (const int*)d_in[17];
    const float* pt    = (const float*)d_in[18];

    int D = in_sizes[2];         // 128
    int B = in_sizes[12];        // 4
    int L = in_sizes[13] / B;    // 128

    // workspace carve-up: stamped exchange buffers first (8B aligned)
    u64*   h1st     = (u64*)d_ws;                           // 4*512 stamped words
    u64*   zpst     = h1st + 4 * 512;                       // 4*1024 stamped words
    float* jsdv     = (float*)(zpst + 4 * 1024);            // B*L
    float* enc      = jsdv + (size_t)B * L;                 // B*L*D
    float* envsb    = enc + (size_t)B * L * D;              // B*MAX_SEG*D
    float* dt_sched = envsb + (size_t)B * MAX_SEG * D;      // B*MAX_T
    int*   envid    = (int*)(dt_sched + (size_t)B * MAX_T); // B*MAX_T
    int*   stateidx = envid + (size_t)B * MAX_T;            // B*L
    int*   Tcnt     = stateidx + (size_t)B * L;             // B

    hipMemsetAsync(h1st, 0, (4 * 512 + 4 * 1024) * sizeof(u64), stream);  // stamps=0 < phase 1
    encode_kernel<<<B * L, D, 0, stream>>>(emb, hi, w1, b1, w2, b2, enc, (float*)d_out, B, L, D);
    jsd_kernel<<<B * 128, 64, 0, stream>>>(enc, hl, jsdv, L, D);
    plan_kernel<<<B, 64, 0, stream>>>(enc, ht, hl, pt, jsdv, envsb, dt_sched, envid, stateidx, Tcnt, B, L, D);
    ode_coop<<<8 * NWGB, 512, 0, stream>>>(usert, u, vw1, vb1, vw2, vb2, vw3, vb3, emb, pos, neg,
                                           envsb, dt_sched, envid, stateidx, Tcnt,
                                           h1st, zpst, (float*)d_out, B);
}